// Round 1
// baseline (1012.614 us; speedup 1.0000x reference)
//
#include <hip/hip_runtime.h>
#include <math.h>

#define NVEH 400000
#define NTOT 500000
#define NEDGE 16000000
#define DT 0.2f
#define SAFE_C 1.5f
#define PARK_C 5.0f
#define RADIUS_C 1.5f
#define DEFV_C 2.5f

// ws layout (bytes):
//   A        @ 0         : NTOT * float4  = 8,000,000   (pred_x, pred_y, ref_x, ref_y)
//   B        @ 8,000,000 : NTOT * float2  = 4,000,000   (|speed|, col7)
//   basediff @12,000,000 : NVEH * float   = 1,600,000   (||pos_pred|| - ||pos_ref||)
//   mask     @13,600,000 : NVEH * float   = 1,600,000
//   segdiff  @15,200,000 : NVEH * float   = 1,600,000   (zeroed each launch)
//   accum    @16,800,000 : 2 * double     = 16          (zeroed each launch)

__global__ __launch_bounds__(256) void node_kernel(
    const float* __restrict__ yp, const float* __restrict__ yr,
    const float* __restrict__ X, const float* __restrict__ be,
    float4* __restrict__ A, float2* __restrict__ B,
    float* __restrict__ basediff, float* __restrict__ maskArr,
    double* __restrict__ accum)
{
    int i = blockIdx.x * blockDim.x + threadIdx.x;
    double local = 0.0;
    if (i < NTOT) {
        const float* row = X + (size_t)i * 9;
        if (i < NVEH) {
            float x0 = row[0], x1 = row[1], psi = row[2], v = row[3];
            float p4 = row[4], p5 = row[5], x7 = row[7];
            float yr0 = yr[2 * i], yr1 = yr[2 * i + 1];
            float yp0 = yp[2 * i], yp1 = yp[2 * i + 1];

            // vehicle dynamics (psi_t is never used downstream -> skipped)
            float xt = x0 + v * cosf(psi) * DT;
            float yt = x1 + v * sinf(psi) * DT;
            float vt = 0.99f * v + yr0 * DT;

            // updated speed for collision model
            float speed = vt + (yp0 - yr0) * DT;
            float ct = cosf(yr1), st = sinf(yr1);
            float ppx = xt + ct * speed * DT;
            float ppy = yt + st * speed * DT;

            A[i] = make_float4(ppx, ppy, xt, yt);
            B[i] = make_float2(fabsf(speed), x7);

            float nrm_pred = sqrtf(ppx * ppx + ppy * ppy);
            float nrm_ref  = sqrtf(xt * xt + yt * yt);
            basediff[i] = nrm_pred - nrm_ref;

            // masks
            float dx = xt - p4, dy = yt - p5;
            bool m1 = (sqrtf(dx * dx + dy * dy) - (PARK_C + fabsf(v))) > 0.0f;
            bool m2 = fabsf(vt) >= (DEFV_C - 1e-5f);
            float sg = (vt > 0.0f) ? 1.0f : ((vt < 0.0f) ? -1.0f : 0.0f);
            bool m3 = sg * (yr0 - yp0) <= 1e-5f;
            float mask = (m1 && m2 && m3) ? 1.0f : 0.0f;
            maskArr[i] = mask;

            // edge-independent loss terms
            float t1 = (yr1 - yp1) * 1.25f;           // / BOUND1 (0.8)
            float l1 = t1 * t1;                       // loss_1 term
            float t2 = yr0 - yp0;                     // / BOUND0 (1.0)
            float l21 = t2 * t2;                      // loss_2_1 term
            float b0 = be[2 * i], b1 = be[2 * i + 1];
            float b1s = b1 * 1.25f;
            float l3 = b0 * b0 + b1s * b1s;           // loss_3 term

            local = (double)l1 + (double)((1.0f - mask) * l21) + 0.1 * (double)l3;
        } else {
            float x0 = row[0], x1 = row[1], v = row[3], x7 = row[7];
            A[i] = make_float4(x0, x1, x0, x1);
            B[i] = make_float2(fabsf(v), x7);
        }
    }
    // wave-level double reduction -> one atomic per wave
    for (int off = 32; off > 0; off >>= 1)
        local += __shfl_down(local, off, 64);
    if ((threadIdx.x & 63) == 0 && local != 0.0)
        atomicAdd(accum, local);
}

__global__ __launch_bounds__(256) void edge_kernel(
    const int* __restrict__ e0p, const int* __restrict__ e1p,
    const float4* __restrict__ A, const float2* __restrict__ B,
    float* __restrict__ segdiff)
{
    int e = blockIdx.x * blockDim.x + threadIdx.x;
    if (e >= NEDGE) return;
    int a = __builtin_nontemporal_load(e0p + e);
    int b = __builtin_nontemporal_load(e1p + e);

    float4 Aa = A[a];
    float4 Ab = A[b];
    float2 Ba = B[a];
    float2 Bb = B[b];

    bool veh = a < NVEH;
    float safe = Bb.x + (veh ? Ba.x : 0.0f) + SAFE_C;
    float base = safe + Ba.y + (veh ? 2.0f : 1.0f) * RADIUS_C;

    float dxp = Aa.x - Ab.x, dyp = Aa.y - Ab.y;
    float dp = sqrtf(dxp * dxp + dyp * dyp);
    float lcp = fmaxf(base - dp, 0.0f);

    float dxr = Aa.z - Ab.z, dyr = Aa.w - Ab.w;
    float dr = sqrtf(dxr * dxr + dyr * dyr);
    float lcr = fmaxf(base - dr, 0.0f);

    float diff = (lcp * lcp + lcp) - (lcr * lcr + lcr);
    if (b < NVEH && diff != 0.0f)
        atomicAdd(segdiff + b, diff);
}

__global__ __launch_bounds__(256) void final_kernel(
    const float* __restrict__ basediff, const float* __restrict__ segdiff,
    const float* __restrict__ maskArr, double* __restrict__ accum)
{
    int i = blockIdx.x * blockDim.x + threadIdx.x;
    double local = 0.0;
    if (i < NVEH) {
        float m = maskArr[i];
        if (m != 0.0f) {
            float d = basediff[i] + segdiff[i];
            float f = (d >= 0.0f) ? (d * d + d) : d;
            local = (double)f;
        }
    }
    for (int off = 32; off > 0; off >>= 1)
        local += __shfl_down(local, off, 64);
    if ((threadIdx.x & 63) == 0 && local != 0.0)
        atomicAdd(accum + 1, local);
}

__global__ void finish_kernel(const double* __restrict__ accum, float* __restrict__ out)
{
    out[0] = (float)((accum[0] + accum[1]) * (1.0 / (double)NVEH));
}

extern "C" void kernel_launch(void* const* d_in, const int* in_sizes, int n_in,
                              void* d_out, int out_size, void* d_ws, size_t ws_size,
                              hipStream_t stream) {
    const float* yp = (const float*)d_in[0];   // y_pred  (NV,2)
    const float* yr = (const float*)d_in[1];   // y_ref   (NV,2)
    const float* X  = (const float*)d_in[2];   // X_cur   (N,9)
    const int*   ed = (const int*)d_in[3];     // edges   (2,E)
    const float* be = (const float*)d_in[4];   // be_static (NV,2)
    float* out = (float*)d_out;

    char* ws = (char*)d_ws;
    float4* A        = (float4*)(ws + 0);
    float2* B        = (float2*)(ws + 8000000);
    float*  basediff = (float*) (ws + 12000000);
    float*  maskArr  = (float*) (ws + 13600000);
    float*  segdiff  = (float*) (ws + 15200000);
    double* accum    = (double*)(ws + 16800000);

    // zero segdiff + accum in one contiguous memset (ws is re-poisoned each call)
    hipMemsetAsync(segdiff, 0, (size_t)NVEH * sizeof(float) + 2 * sizeof(double), stream);

    node_kernel<<<(NTOT + 255) / 256, 256, 0, stream>>>(
        yp, yr, X, be, A, B, basediff, maskArr, accum);

    edge_kernel<<<(NEDGE + 255) / 256, 256, 0, stream>>>(
        ed, ed + NEDGE, A, B, segdiff);

    final_kernel<<<(NVEH + 255) / 256, 256, 0, stream>>>(
        basediff, segdiff, maskArr, accum);

    finish_kernel<<<1, 1, 0, stream>>>(accum, out);
}

// Round 2
// 914.614 us; speedup vs baseline: 1.1071x; 1.1071x over previous
//
#include <hip/hip_runtime.h>
#include <math.h>

#define NVEH 400000
#define NTOT 500000
#define NEDGE 16000000
#define DT 0.2f
#define SAFE_C 1.5f
#define PARK_C 5.0f
#define RADIUS_C 1.5f
#define DEFV_C 2.5f

// ws layout (bytes):
//   T        @ 0         : NTOT * 32B    = 16,000,000  (per node: {pred_x,pred_y,ref_x,ref_y}, {g,h,-,-})
//   basediff @16,000,000 : NVEH * float  =  1,600,000  (||pos_pred|| - ||pos_ref||)
//   mask     @17,600,000 : NVEH * float  =  1,600,000
//   segdiff  @19,200,000 : NVEH * float  =  1,600,000  (zeroed each launch)
//   accum    @20,800,000 : 2 * double    = 16          (zeroed each launch)
//
// g = col7 + RADIUS + (node<NVEH ? |speed| + RADIUS : 0)   (e0-role scalar)
// h = |speed| + SAFE                                        (e1-role scalar)
// per-edge: base = g[e0] + h[e1]  — ONE 32B gather per endpoint (one cache line)

__global__ __launch_bounds__(256) void node_kernel(
    const float* __restrict__ yp, const float* __restrict__ yr,
    const float* __restrict__ X, const float* __restrict__ be,
    float4* __restrict__ T,
    float* __restrict__ basediff, float* __restrict__ maskArr,
    double* __restrict__ accum)
{
    int i = blockIdx.x * blockDim.x + threadIdx.x;
    double local = 0.0;
    if (i < NTOT) {
        const float* row = X + (size_t)i * 9;
        if (i < NVEH) {
            float x0 = row[0], x1 = row[1], psi = row[2], v = row[3];
            float p4 = row[4], p5 = row[5], x7 = row[7];
            float yr0 = yr[2 * i], yr1 = yr[2 * i + 1];
            float yp0 = yp[2 * i], yp1 = yp[2 * i + 1];

            // vehicle dynamics (psi_t is never consumed downstream -> skipped)
            float xt = x0 + v * cosf(psi) * DT;
            float yt = x1 + v * sinf(psi) * DT;
            float vt = 0.99f * v + yr0 * DT;

            // updated speed for collision model
            float speed = vt + (yp0 - yr0) * DT;
            float ct = cosf(yr1), st = sinf(yr1);
            float ppx = xt + ct * speed * DT;
            float ppy = yt + st * speed * DT;

            float as = fabsf(speed);
            T[2 * i]     = make_float4(ppx, ppy, xt, yt);
            T[2 * i + 1] = make_float4(x7 + RADIUS_C + as + RADIUS_C,  // g (vehicle)
                                       as + SAFE_C,                     // h
                                       0.0f, 0.0f);

            float nrm_pred = sqrtf(ppx * ppx + ppy * ppy);
            float nrm_ref  = sqrtf(xt * xt + yt * yt);
            basediff[i] = nrm_pred - nrm_ref;

            // masks
            float dx = xt - p4, dy = yt - p5;
            bool m1 = (sqrtf(dx * dx + dy * dy) - (PARK_C + fabsf(v))) > 0.0f;
            bool m2 = fabsf(vt) >= (DEFV_C - 1e-5f);
            float sg = (vt > 0.0f) ? 1.0f : ((vt < 0.0f) ? -1.0f : 0.0f);
            bool m3 = sg * (yr0 - yp0) <= 1e-5f;
            float mask = (m1 && m2 && m3) ? 1.0f : 0.0f;
            maskArr[i] = mask;

            // edge-independent loss terms
            float t1 = (yr1 - yp1) * 1.25f;           // / BOUND1 (0.8)
            float l1 = t1 * t1;                       // loss_1 term
            float t2 = yr0 - yp0;                     // / BOUND0 (1.0)
            float l21 = t2 * t2;                      // loss_2_1 term
            float b0 = be[2 * i], b1 = be[2 * i + 1];
            float b1s = b1 * 1.25f;
            float l3 = b0 * b0 + b1s * b1s;           // loss_3 term

            local = (double)l1 + (double)((1.0f - mask) * l21) + 0.1 * (double)l3;
        } else {
            float x0 = row[0], x1 = row[1], v = row[3], x7 = row[7];
            float av = fabsf(v);
            T[2 * i]     = make_float4(x0, x1, x0, x1);
            T[2 * i + 1] = make_float4(x7 + RADIUS_C,   // g (non-vehicle)
                                       av + SAFE_C,     // h
                                       0.0f, 0.0f);
        }
    }
    // wave-level double reduction -> one atomic per wave
    for (int off = 32; off > 0; off >>= 1)
        local += __shfl_down(local, off, 64);
    if ((threadIdx.x & 63) == 0 && local != 0.0)
        atomicAdd(accum, local);
}

__global__ __launch_bounds__(256) void edge_kernel(
    const int* __restrict__ e0p, const int* __restrict__ e1p,
    const float4* __restrict__ T,
    float* __restrict__ segdiff)
{
    int e = blockIdx.x * blockDim.x + threadIdx.x;
    if (e >= NEDGE) return;
    int a = __builtin_nontemporal_load(e0p + e);
    int b = __builtin_nontemporal_load(e1p + e);

    float4 pa = T[2 * a];        // same 32B record -> one cache line
    float4 sa = T[2 * a + 1];
    float4 pb = T[2 * b];
    float4 sb = T[2 * b + 1];

    float base = sa.x + sb.y;    // g[a] + h[b]

    float dxp = pa.x - pb.x, dyp = pa.y - pb.y;
    float dp = sqrtf(dxp * dxp + dyp * dyp);
    float lcp = fmaxf(base - dp, 0.0f);

    float dxr = pa.z - pb.z, dyr = pa.w - pb.w;
    float dr = sqrtf(dxr * dxr + dyr * dyr);
    float lcr = fmaxf(base - dr, 0.0f);

    float diff = (lcp * lcp + lcp) - (lcr * lcr + lcr);
    if (b < NVEH && diff != 0.0f)
        atomicAdd(segdiff + b, diff);
}

__global__ __launch_bounds__(256) void final_kernel(
    const float* __restrict__ basediff, const float* __restrict__ segdiff,
    const float* __restrict__ maskArr, double* __restrict__ accum)
{
    int i = blockIdx.x * blockDim.x + threadIdx.x;
    double local = 0.0;
    if (i < NVEH) {
        float m = maskArr[i];
        if (m != 0.0f) {
            float d = basediff[i] + segdiff[i];
            float f = (d >= 0.0f) ? (d * d + d) : d;
            local = (double)f;
        }
    }
    for (int off = 32; off > 0; off >>= 1)
        local += __shfl_down(local, off, 64);
    if ((threadIdx.x & 63) == 0 && local != 0.0)
        atomicAdd(accum + 1, local);
}

__global__ void finish_kernel(const double* __restrict__ accum, float* __restrict__ out)
{
    out[0] = (float)((accum[0] + accum[1]) * (1.0 / (double)NVEH));
}

extern "C" void kernel_launch(void* const* d_in, const int* in_sizes, int n_in,
                              void* d_out, int out_size, void* d_ws, size_t ws_size,
                              hipStream_t stream) {
    const float* yp = (const float*)d_in[0];   // y_pred  (NV,2)
    const float* yr = (const float*)d_in[1];   // y_ref   (NV,2)
    const float* X  = (const float*)d_in[2];   // X_cur   (N,9)
    const int*   ed = (const int*)d_in[3];     // edges   (2,E)
    const float* be = (const float*)d_in[4];   // be_static (NV,2)
    float* out = (float*)d_out;

    char* ws = (char*)d_ws;
    float4* T        = (float4*)(ws + 0);
    float*  basediff = (float*) (ws + 16000000);
    float*  maskArr  = (float*) (ws + 17600000);
    float*  segdiff  = (float*) (ws + 19200000);
    double* accum    = (double*)(ws + 20800000);

    // zero segdiff + accum in one contiguous memset (ws is re-poisoned each call)
    hipMemsetAsync(segdiff, 0, (size_t)NVEH * sizeof(float) + 2 * sizeof(double), stream);

    node_kernel<<<(NTOT + 255) / 256, 256, 0, stream>>>(
        yp, yr, X, be, T, basediff, maskArr, accum);

    edge_kernel<<<(NEDGE + 255) / 256, 256, 0, stream>>>(
        ed, ed + NEDGE, T, segdiff);

    final_kernel<<<(NVEH + 255) / 256, 256, 0, stream>>>(
        basediff, segdiff, maskArr, accum);

    finish_kernel<<<1, 1, 0, stream>>>(accum, out);
}

// Round 3
// 878.985 us; speedup vs baseline: 1.1520x; 1.0405x over previous
//
#include <hip/hip_runtime.h>
#include <hip/hip_fp16.h>
#include <math.h>

#define NVEH 400000
#define NTOT 500000
#define NEDGE 16000000
#define DT 0.2f
#define SAFE_C 1.5f
#define PARK_C 5.0f
#define RADIUS_C 1.5f
#define DEFV_C 2.5f

// ws layout (bytes):
//   T        @ 0          : NTOT * 16B   = 8,000,000
//       per node: {xt:f32, yt:f32, (dx,dy):2xfp16, (g,h):2xfp16}
//       pred_pos = (xt+dx, yt+dy);  g = col7+R+veh*(|s|+R);  h = |s|+SAFE
//   basediff @  8,000,000 : NVEH * float = 1,600,000
//   mask     @  9,600,000 : NVEH * float = 1,600,000
//   segdiff  @ 11,200,000 : NVEH * float = 1,600,000  (zeroed each launch)
//   accum    @ 12,800,000 : 2 * double   = 16         (zeroed each launch)

__global__ __launch_bounds__(256) void node_kernel(
    const float* __restrict__ yp, const float* __restrict__ yr,
    const float* __restrict__ X, const float* __restrict__ be,
    float4* __restrict__ T,
    float* __restrict__ basediff, float* __restrict__ maskArr,
    double* __restrict__ accum)
{
    int i = blockIdx.x * blockDim.x + threadIdx.x;
    double local = 0.0;
    if (i < NTOT) {
        const float* row = X + (size_t)i * 9;
        if (i < NVEH) {
            float x0 = row[0], x1 = row[1], psi = row[2], v = row[3];
            float p4 = row[4], p5 = row[5], x7 = row[7];
            float yr0 = yr[2 * i], yr1 = yr[2 * i + 1];
            float yp0 = yp[2 * i], yp1 = yp[2 * i + 1];

            // vehicle dynamics (psi_t never consumed downstream -> skipped)
            float xt = x0 + v * cosf(psi) * DT;
            float yt = x1 + v * sinf(psi) * DT;
            float vt = 0.99f * v + yr0 * DT;

            // updated speed for collision model
            float speed = vt + (yp0 - yr0) * DT;
            float ct = cosf(yr1), st = sinf(yr1);
            float dX = ct * speed * DT;   // pred-pos offset
            float dY = st * speed * DT;
            float ppx = xt + dX, ppy = yt + dY;

            float as = fabsf(speed);
            __half2 hd = __floats2half2_rn(dX, dY);
            __half2 hg = __floats2half2_rn(x7 + RADIUS_C + as + RADIUS_C,  // g
                                           as + SAFE_C);                    // h
            float4 rec;
            rec.x = xt; rec.y = yt;
            rec.z = __uint_as_float(*(unsigned int*)&hd);
            rec.w = __uint_as_float(*(unsigned int*)&hg);
            T[i] = rec;

            float nrm_pred = sqrtf(ppx * ppx + ppy * ppy);
            float nrm_ref  = sqrtf(xt * xt + yt * yt);
            basediff[i] = nrm_pred - nrm_ref;

            // masks
            float dx = xt - p4, dy = yt - p5;
            bool m1 = (sqrtf(dx * dx + dy * dy) - (PARK_C + fabsf(v))) > 0.0f;
            bool m2 = fabsf(vt) >= (DEFV_C - 1e-5f);
            float sg = (vt > 0.0f) ? 1.0f : ((vt < 0.0f) ? -1.0f : 0.0f);
            bool m3 = sg * (yr0 - yp0) <= 1e-5f;
            float mask = (m1 && m2 && m3) ? 1.0f : 0.0f;
            maskArr[i] = mask;

            // edge-independent loss terms
            float t1 = (yr1 - yp1) * 1.25f;           // / BOUND1 (0.8)
            float l1 = t1 * t1;
            float t2 = yr0 - yp0;                     // / BOUND0 (1.0)
            float l21 = t2 * t2;
            float b0 = be[2 * i], b1 = be[2 * i + 1];
            float b1s = b1 * 1.25f;
            float l3 = b0 * b0 + b1s * b1s;

            local = (double)l1 + (double)((1.0f - mask) * l21) + 0.1 * (double)l3;
        } else {
            float x0 = row[0], x1 = row[1], v = row[3], x7 = row[7];
            float av = fabsf(v);
            __half2 hd = __floats2half2_rn(0.0f, 0.0f);
            __half2 hg = __floats2half2_rn(x7 + RADIUS_C,   // g (non-vehicle)
                                           av + SAFE_C);     // h
            float4 rec;
            rec.x = x0; rec.y = x1;
            rec.z = __uint_as_float(*(unsigned int*)&hd);
            rec.w = __uint_as_float(*(unsigned int*)&hg);
            T[i] = rec;
        }
    }
    // wave-level double reduction -> one atomic per wave
    for (int off = 32; off > 0; off >>= 1)
        local += __shfl_down(local, off, 64);
    if ((threadIdx.x & 63) == 0 && local != 0.0)
        atomicAdd(accum, local);
}

__global__ __launch_bounds__(256) void edge_kernel(
    const int* __restrict__ e0p, const int* __restrict__ e1p,
    const float4* __restrict__ T,
    float* __restrict__ segdiff)
{
    int e = blockIdx.x * blockDim.x + threadIdx.x;
    if (e >= NEDGE) return;
    int b = __builtin_nontemporal_load(e1p + e);
    if (b >= NVEH) return;            // contributes nothing: skip gathers entirely
    int a = __builtin_nontemporal_load(e0p + e);

    float4 ra = T[a];                 // one dwordx4 per endpoint
    float4 rb = T[b];

    unsigned int za = __float_as_uint(ra.z), wa = __float_as_uint(ra.w);
    unsigned int zb = __float_as_uint(rb.z), wb = __float_as_uint(rb.w);
    float2 Da = __half22float2(*(__half2*)&za);
    float2 Db = __half22float2(*(__half2*)&zb);
    float g_a = __low2float(*(__half2*)&wa);
    float h_b = __high2float(*(__half2*)&wb);

    float base = g_a + h_b;

    float dxr = ra.x - rb.x, dyr = ra.y - rb.y;
    float dr = sqrtf(dxr * dxr + dyr * dyr);
    float lcr = fmaxf(base - dr, 0.0f);

    float dxp = dxr + (Da.x - Db.x), dyp = dyr + (Da.y - Db.y);
    float dp = sqrtf(dxp * dxp + dyp * dyp);
    float lcp = fmaxf(base - dp, 0.0f);

    float diff = (lcp * lcp + lcp) - (lcr * lcr + lcr);
    if (diff != 0.0f)
        atomicAdd(segdiff + b, diff);
}

__global__ __launch_bounds__(256) void final_kernel(
    const float* __restrict__ basediff, const float* __restrict__ segdiff,
    const float* __restrict__ maskArr, double* __restrict__ accum)
{
    int i = blockIdx.x * blockDim.x + threadIdx.x;
    double local = 0.0;
    if (i < NVEH) {
        float m = maskArr[i];
        if (m != 0.0f) {
            float d = basediff[i] + segdiff[i];
            float f = (d >= 0.0f) ? (d * d + d) : d;
            local = (double)f;
        }
    }
    for (int off = 32; off > 0; off >>= 1)
        local += __shfl_down(local, off, 64);
    if ((threadIdx.x & 63) == 0 && local != 0.0)
        atomicAdd(accum + 1, local);
}

__global__ void finish_kernel(const double* __restrict__ accum, float* __restrict__ out)
{
    out[0] = (float)((accum[0] + accum[1]) * (1.0 / (double)NVEH));
}

extern "C" void kernel_launch(void* const* d_in, const int* in_sizes, int n_in,
                              void* d_out, int out_size, void* d_ws, size_t ws_size,
                              hipStream_t stream) {
    const float* yp = (const float*)d_in[0];   // y_pred  (NV,2)
    const float* yr = (const float*)d_in[1];   // y_ref   (NV,2)
    const float* X  = (const float*)d_in[2];   // X_cur   (N,9)
    const int*   ed = (const int*)d_in[3];     // edges   (2,E)
    const float* be = (const float*)d_in[4];   // be_static (NV,2)
    float* out = (float*)d_out;

    char* ws = (char*)d_ws;
    float4* T        = (float4*)(ws + 0);
    float*  basediff = (float*) (ws + 8000000);
    float*  maskArr  = (float*) (ws + 9600000);
    float*  segdiff  = (float*) (ws + 11200000);
    double* accum    = (double*)(ws + 12800000);

    // zero segdiff + accum in one contiguous memset (ws is re-poisoned each call)
    hipMemsetAsync(segdiff, 0, (size_t)NVEH * sizeof(float) + 2 * sizeof(double), stream);

    node_kernel<<<(NTOT + 255) / 256, 256, 0, stream>>>(
        yp, yr, X, be, T, basediff, maskArr, accum);

    edge_kernel<<<(NEDGE + 255) / 256, 256, 0, stream>>>(
        ed, ed + NEDGE, T, segdiff);

    final_kernel<<<(NVEH + 255) / 256, 256, 0, stream>>>(
        basediff, segdiff, maskArr, accum);

    finish_kernel<<<1, 1, 0, stream>>>(accum, out);
}

// Round 4
// 272.260 us; speedup vs baseline: 3.7193x; 3.2285x over previous
//
#include <hip/hip_runtime.h>
#include <math.h>

#define NVEH 400000
#define NTOT 500000
#define NEDGE 16000000
#define DT 0.2f
#define SAFE_C 1.5f
#define PARK_C 5.0f
#define RADIUS_C 1.5f
#define DEFV_C 2.5f
#define LIST_CAP 4096     // ids stored in ws
#define LIST_USE 128      // use LDS-list path iff count <= this

// ws layout (bytes):
//   T        @ 0          : NTOT * 32B   = 16,000,000
//       T[2i]   = {pred_x, pred_y, ref_x, ref_y}  (fp32)
//       T[2i+1] = {g, h, 0, 0}                    (fp32)
//       g = col7 + R + veh*(|s|+R)  (e0-role),  h = |s| + SAFE  (e1-role)
//   basediff @ 16,000,000 : NVEH * float = 1,600,000
//   maskArr  @ 17,600,000 : NVEH * float = 1,600,000  (also the fallback active table)
//   segdiff  @ 19,200,000 : NVEH * float = 1,600,000  [memset 0]
//   accum    @ 20,800,000 : 2 * double   = 16         [memset 0]
//   count    @ 20,800,016 : int          = 4          [memset 0]
//   ids      @ 20,800,032 : LIST_CAP * int

__global__ __launch_bounds__(256) void node_kernel(
    const float* __restrict__ yp, const float* __restrict__ yr,
    const float* __restrict__ X, const float* __restrict__ be,
    float4* __restrict__ T,
    float* __restrict__ basediff, float* __restrict__ maskArr,
    double* __restrict__ accum, int* __restrict__ countp, int* __restrict__ ids)
{
    int i = blockIdx.x * blockDim.x + threadIdx.x;
    double local = 0.0;
    if (i < NTOT) {
        const float* row = X + (size_t)i * 9;
        if (i < NVEH) {
            float x0 = row[0], x1 = row[1], psi = row[2], v = row[3];
            float p4 = row[4], p5 = row[5], x7 = row[7];
            float yr0 = yr[2 * i], yr1 = yr[2 * i + 1];
            float yp0 = yp[2 * i], yp1 = yp[2 * i + 1];

            // vehicle dynamics (psi_t never consumed downstream -> skipped)
            float xt = x0 + v * cosf(psi) * DT;
            float yt = x1 + v * sinf(psi) * DT;
            float vt = 0.99f * v + yr0 * DT;

            // updated speed for collision model
            float speed = vt + (yp0 - yr0) * DT;
            float ct = cosf(yr1), st = sinf(yr1);
            float ppx = xt + ct * speed * DT;
            float ppy = yt + st * speed * DT;

            float as = fabsf(speed);
            T[2 * i]     = make_float4(ppx, ppy, xt, yt);
            T[2 * i + 1] = make_float4(x7 + RADIUS_C + as + RADIUS_C,  // g
                                       as + SAFE_C, 0.0f, 0.0f);       // h

            float nrm_pred = sqrtf(ppx * ppx + ppy * ppy);
            float nrm_ref  = sqrtf(xt * xt + yt * yt);
            basediff[i] = nrm_pred - nrm_ref;

            // masks
            float dx = xt - p4, dy = yt - p5;
            bool m1 = (sqrtf(dx * dx + dy * dy) - (PARK_C + fabsf(v))) > 0.0f;
            bool m2 = fabsf(vt) >= (DEFV_C - 1e-5f);
            float sg = (vt > 0.0f) ? 1.0f : ((vt < 0.0f) ? -1.0f : 0.0f);
            bool m3 = sg * (yr0 - yp0) <= 1e-5f;
            bool msk = m1 && m2 && m3;
            maskArr[i] = msk ? 1.0f : 0.0f;
            if (msk) {
                int idx = atomicAdd(countp, 1);
                if (idx < LIST_CAP) ids[idx] = i;
            }

            // edge-independent loss terms
            float t1 = (yr1 - yp1) * 1.25f;           // / BOUND1 (0.8)
            float l1 = t1 * t1;
            float t2 = yr0 - yp0;                     // / BOUND0 (1.0)
            float l21 = t2 * t2;
            float b0 = be[2 * i], b1 = be[2 * i + 1];
            float b1s = b1 * 1.25f;
            float l3 = b0 * b0 + b1s * b1s;

            local = (double)l1 + (double)((msk ? 0.0f : 1.0f) * l21) + 0.1 * (double)l3;
        } else {
            float x0 = row[0], x1 = row[1], v = row[3], x7 = row[7];
            T[2 * i]     = make_float4(x0, x1, x0, x1);
            T[2 * i + 1] = make_float4(x7 + RADIUS_C, fabsf(v) + SAFE_C, 0.0f, 0.0f);
        }
    }
    // wave-level double reduction -> one atomic per wave
    for (int off = 32; off > 0; off >>= 1)
        local += __shfl_down(local, off, 64);
    if ((threadIdx.x & 63) == 0 && local != 0.0)
        atomicAdd(accum, local);
}

__device__ __forceinline__ void edge_compute(
    int a, int b, const float4* __restrict__ T, float* __restrict__ segdiff)
{
    float4 pa = T[2 * a];
    float4 sa = T[2 * a + 1];
    float4 pb = T[2 * b];
    float4 sb = T[2 * b + 1];

    float base = sa.x + sb.y;    // g[a] + h[b]

    float dxp = pa.x - pb.x, dyp = pa.y - pb.y;
    float dp = sqrtf(dxp * dxp + dyp * dyp);
    float lcp = fmaxf(base - dp, 0.0f);

    float dxr = pa.z - pb.z, dyr = pa.w - pb.w;
    float dr = sqrtf(dxr * dxr + dyr * dyr);
    float lcr = fmaxf(base - dr, 0.0f);

    float diff = (lcp * lcp + lcp) - (lcr * lcr + lcr);
    if (diff != 0.0f)
        atomicAdd(segdiff + b, diff);
}

__global__ __launch_bounds__(256) void edge_kernel(
    const int* __restrict__ e0p, const int* __restrict__ e1p,
    const float4* __restrict__ T, const float* __restrict__ maskArr,
    float* __restrict__ segdiff,
    const int* __restrict__ countp, const int* __restrict__ ids)
{
    __shared__ int s_ids[LIST_USE];
    int cnt = *countp;
    int e = blockIdx.x * blockDim.x + threadIdx.x;

    if (cnt <= LIST_USE) {
        // typical path: ~7 active vehicles -> pure coalesced e1 scan + compares
        if (threadIdx.x < cnt) s_ids[threadIdx.x] = ids[threadIdx.x];
        __syncthreads();
        if (e >= NEDGE) return;
        int b = __builtin_nontemporal_load(e1p + e);
        bool hit = false;
        for (int j = 0; j < cnt; ++j)
            hit |= (b == s_ids[j]);
        if (hit) {
            int a = e0p[e];
            edge_compute(a, b, T, segdiff);
        }
    } else {
        // robust fallback: gather the mask table per edge (R3-style)
        if (e >= NEDGE) return;
        int b = __builtin_nontemporal_load(e1p + e);
        if (b < NVEH && maskArr[b] != 0.0f) {
            int a = e0p[e];
            edge_compute(a, b, T, segdiff);
        }
    }
}

__global__ __launch_bounds__(256) void final_kernel(
    const float* __restrict__ basediff, const float* __restrict__ segdiff,
    const float* __restrict__ maskArr, double* __restrict__ accum)
{
    int i = blockIdx.x * blockDim.x + threadIdx.x;
    double local = 0.0;
    if (i < NVEH) {
        float m = maskArr[i];
        if (m != 0.0f) {
            float d = basediff[i] + segdiff[i];
            float f = (d >= 0.0f) ? (d * d + d) : d;
            local = (double)f;
        }
    }
    for (int off = 32; off > 0; off >>= 1)
        local += __shfl_down(local, off, 64);
    if ((threadIdx.x & 63) == 0 && local != 0.0)
        atomicAdd(accum + 1, local);
}

__global__ void finish_kernel(const double* __restrict__ accum, float* __restrict__ out)
{
    out[0] = (float)((accum[0] + accum[1]) * (1.0 / (double)NVEH));
}

extern "C" void kernel_launch(void* const* d_in, const int* in_sizes, int n_in,
                              void* d_out, int out_size, void* d_ws, size_t ws_size,
                              hipStream_t stream) {
    const float* yp = (const float*)d_in[0];   // y_pred  (NV,2)
    const float* yr = (const float*)d_in[1];   // y_ref   (NV,2)
    const float* X  = (const float*)d_in[2];   // X_cur   (N,9)
    const int*   ed = (const int*)d_in[3];     // edges   (2,E)
    const float* be = (const float*)d_in[4];   // be_static (NV,2)
    float* out = (float*)d_out;

    char* ws = (char*)d_ws;
    float4* T        = (float4*)(ws + 0);
    float*  basediff = (float*) (ws + 16000000);
    float*  maskArr  = (float*) (ws + 17600000);
    float*  segdiff  = (float*) (ws + 19200000);
    double* accum    = (double*)(ws + 20800000);
    int*    countp   = (int*)   (ws + 20800016);
    int*    ids      = (int*)   (ws + 20800032);

    // zero segdiff + accum + count in one contiguous memset
    hipMemsetAsync(segdiff, 0, 1600032, stream);

    node_kernel<<<(NTOT + 255) / 256, 256, 0, stream>>>(
        yp, yr, X, be, T, basediff, maskArr, accum, countp, ids);

    edge_kernel<<<(NEDGE + 255) / 256, 256, 0, stream>>>(
        ed, ed + NEDGE, T, maskArr, segdiff, countp, ids);

    final_kernel<<<(NVEH + 255) / 256, 256, 0, stream>>>(
        basediff, segdiff, maskArr, accum);

    finish_kernel<<<1, 1, 0, stream>>>(accum, out);
}

// Round 5
// 208.208 us; speedup vs baseline: 4.8635x; 1.3076x over previous
//
#include <hip/hip_runtime.h>
#include <math.h>

#define NVEH 400000
#define NTOT 500000
#define NEDGE 16000000
#define DT 0.2f
#define SAFE_C 1.5f
#define PARK_C 5.0f
#define RADIUS_C 1.5f
#define DEFV_C 2.5f
#define LIST_CAP 4096     // ids stored in ws
#define LIST_USE 128      // LDS-list path iff count <= this
#define REG_USE 16        // registerized compare path iff count <= this

#define NODE_BLOCKS ((NTOT + 255) / 256)         // 1954
#define NODE_WAVES  (NODE_BLOCKS * 4)            // 7816

// ws layout (bytes):
//   pos      @ 0          : NTOT * float4 = 8,000,000   {pred_x,pred_y,ref_x,ref_y}
//   gh       @  8,000,000 : NTOT * float2 = 4,000,000   {g, h}
//   basediff @ 12,000,000 : NVEH * float  = 1,600,000
//   maskArr  @ 13,600,000 : NVEH * float  = 1,600,000   (fallback path only)
//   segdiff  @ 15,200,000 : NVEH * float  = 1,600,000   [memset 0]
//   count    @ 16,800,000 : int                          [memset 0]
//   ids      @ 16,800,016 : LIST_CAP * int
//   partials @ 16,816,400 : NODE_WAVES * double = 62,528
//
// g = col7 + R + veh*(|s|+R)  (e0-role),  h = |s| + SAFE  (e1-role)

__global__ __launch_bounds__(256) void node_kernel(
    const float* __restrict__ yp, const float* __restrict__ yr,
    const float* __restrict__ X, const float* __restrict__ be,
    float4* __restrict__ pos, float2* __restrict__ gh,
    float* __restrict__ basediff, float* __restrict__ maskArr,
    int* __restrict__ countp, int* __restrict__ ids,
    double* __restrict__ partials)
{
    int i = blockIdx.x * blockDim.x + threadIdx.x;
    double local = 0.0;
    if (i < NTOT) {
        const float* row = X + (size_t)i * 9;
        if (i < NVEH) {
            float x0 = row[0], x1 = row[1], psi = row[2], v = row[3];
            float p4 = row[4], p5 = row[5], x7 = row[7];
            float yr0 = yr[2 * i], yr1 = yr[2 * i + 1];
            float yp0 = yp[2 * i], yp1 = yp[2 * i + 1];

            // vehicle dynamics (psi_t never consumed downstream -> skipped)
            float xt = x0 + v * cosf(psi) * DT;
            float yt = x1 + v * sinf(psi) * DT;
            float vt = 0.99f * v + yr0 * DT;

            // updated speed for collision model
            float speed = vt + (yp0 - yr0) * DT;
            float ct = cosf(yr1), st = sinf(yr1);
            float ppx = xt + ct * speed * DT;
            float ppy = yt + st * speed * DT;

            float as = fabsf(speed);
            pos[i] = make_float4(ppx, ppy, xt, yt);
            gh[i]  = make_float2(x7 + RADIUS_C + as + RADIUS_C, as + SAFE_C);

            float nrm_pred = sqrtf(ppx * ppx + ppy * ppy);
            float nrm_ref  = sqrtf(xt * xt + yt * yt);
            basediff[i] = nrm_pred - nrm_ref;

            // masks
            float dx = xt - p4, dy = yt - p5;
            bool m1 = (sqrtf(dx * dx + dy * dy) - (PARK_C + fabsf(v))) > 0.0f;
            bool m2 = fabsf(vt) >= (DEFV_C - 1e-5f);
            float sg = (vt > 0.0f) ? 1.0f : ((vt < 0.0f) ? -1.0f : 0.0f);
            bool m3 = sg * (yr0 - yp0) <= 1e-5f;
            bool msk = m1 && m2 && m3;
            maskArr[i] = msk ? 1.0f : 0.0f;
            if (msk) {
                int idx = atomicAdd(countp, 1);
                if (idx < LIST_CAP) ids[idx] = i;
            }

            // edge-independent loss terms
            float t1 = (yr1 - yp1) * 1.25f;           // / BOUND1 (0.8)
            float l1 = t1 * t1;
            float t2 = yr0 - yp0;                     // / BOUND0 (1.0)
            float l21 = t2 * t2;
            float b0 = be[2 * i], b1 = be[2 * i + 1];
            float b1s = b1 * 1.25f;
            float l3 = b0 * b0 + b1s * b1s;

            local = (double)l1 + (double)((msk ? 0.0f : 1.0f) * l21) + 0.1 * (double)l3;
        } else {
            float x0 = row[0], x1 = row[1], v = row[3], x7 = row[7];
            pos[i] = make_float4(x0, x1, x0, x1);
            gh[i]  = make_float2(x7 + RADIUS_C, fabsf(v) + SAFE_C);
        }
    }
    // wave-level double reduction -> ONE PLAIN STORE per wave (no atomics)
    for (int off = 32; off > 0; off >>= 1)
        local += __shfl_down(local, off, 64);
    if ((threadIdx.x & 63) == 0)
        partials[blockIdx.x * 4 + (threadIdx.x >> 6)] = local;
}

__device__ __forceinline__ void edge_compute(
    int a, int b, const float4* __restrict__ pos, const float2* __restrict__ gh,
    float* __restrict__ segdiff)
{
    float4 pa = pos[a];
    float4 pb = pos[b];
    float base = gh[a].x + gh[b].y;    // g[a] + h[b]

    float dxp = pa.x - pb.x, dyp = pa.y - pb.y;
    float dp = sqrtf(dxp * dxp + dyp * dyp);
    float lcp = fmaxf(base - dp, 0.0f);

    float dxr = pa.z - pb.z, dyr = pa.w - pb.w;
    float dr = sqrtf(dxr * dxr + dyr * dyr);
    float lcr = fmaxf(base - dr, 0.0f);

    float diff = (lcp * lcp + lcp) - (lcr * lcr + lcr);
    if (diff != 0.0f)
        atomicAdd(segdiff + b, diff);
}

__global__ __launch_bounds__(256) void edge_kernel(
    const int* __restrict__ e0p, const int* __restrict__ e1p,
    const float4* __restrict__ pos, const float2* __restrict__ gh,
    const float* __restrict__ maskArr,
    float* __restrict__ segdiff,
    const int* __restrict__ countp, const int* __restrict__ ids)
{
    __shared__ int s_ids[LIST_USE];
    int cnt = *countp;
    int base = (blockIdx.x * 256 + threadIdx.x) * 4;   // 4 edges per thread

    if (cnt <= LIST_USE) {
        if (threadIdx.x < cnt) s_ids[threadIdx.x] = ids[threadIdx.x];
        __syncthreads();
        int4 bv = *(const int4*)(e1p + base);

        if (cnt <= REG_USE) {
            // branchless registerized membership test (typical: cnt ~ a few)
            int idr[REG_USE];
#pragma unroll
            for (int j = 0; j < REG_USE; ++j)
                idr[j] = (j < cnt) ? s_ids[j] : -1;

            int bs[4] = {bv.x, bv.y, bv.z, bv.w};
#pragma unroll
            for (int k = 0; k < 4; ++k) {
                int b = bs[k];
                bool h = false;
#pragma unroll
                for (int j = 0; j < REG_USE; ++j) h |= (b == idr[j]);
                if (h) {
                    int a = e0p[base + k];
                    edge_compute(a, b, pos, gh, segdiff);
                }
            }
        } else {
            int bs[4] = {bv.x, bv.y, bv.z, bv.w};
#pragma unroll
            for (int k = 0; k < 4; ++k) {
                int b = bs[k];
                bool h = false;
                for (int j = 0; j < cnt; ++j) h |= (b == s_ids[j]);
                if (h) {
                    int a = e0p[base + k];
                    edge_compute(a, b, pos, gh, segdiff);
                }
            }
        }
    } else {
        // robust fallback: per-edge mask gather (statistically never taken)
        for (int k = 0; k < 4; ++k) {
            int b = e1p[base + k];
            if (b < NVEH && maskArr[b] != 0.0f) {
                int a = e0p[base + k];
                edge_compute(a, b, pos, gh, segdiff);
            }
        }
    }
}

__global__ __launch_bounds__(256) void finish_kernel(
    const double* __restrict__ partials,
    const float* __restrict__ basediff, const float* __restrict__ segdiff,
    const float* __restrict__ maskArr,
    const int* __restrict__ countp, const int* __restrict__ ids,
    float* __restrict__ out)
{
    int tid = threadIdx.x;
    double s = 0.0;
    for (int j = tid; j < NODE_WAVES; j += 256)
        s += partials[j];

    int cnt = *countp;
    if (cnt <= LIST_CAP) {
        for (int j = tid; j < cnt; j += 256) {
            int i = ids[j];
            float d = basediff[i] + segdiff[i];
            s += (double)((d >= 0.0f) ? (d * d + d) : d);
        }
    } else {
        // slow-but-correct fallback
        for (int i = tid; i < NVEH; i += 256) {
            if (maskArr[i] != 0.0f) {
                float d = basediff[i] + segdiff[i];
                s += (double)((d >= 0.0f) ? (d * d + d) : d);
            }
        }
    }

    // block reduction (4 waves)
    __shared__ double red[4];
    for (int off = 32; off > 0; off >>= 1)
        s += __shfl_down(s, off, 64);
    if ((tid & 63) == 0) red[tid >> 6] = s;
    __syncthreads();
    if (tid == 0) {
        double t = red[0] + red[1] + red[2] + red[3];
        out[0] = (float)(t * (1.0 / (double)NVEH));
    }
}

extern "C" void kernel_launch(void* const* d_in, const int* in_sizes, int n_in,
                              void* d_out, int out_size, void* d_ws, size_t ws_size,
                              hipStream_t stream) {
    const float* yp = (const float*)d_in[0];   // y_pred  (NV,2)
    const float* yr = (const float*)d_in[1];   // y_ref   (NV,2)
    const float* X  = (const float*)d_in[2];   // X_cur   (N,9)
    const int*   ed = (const int*)d_in[3];     // edges   (2,E)
    const float* be = (const float*)d_in[4];   // be_static (NV,2)
    float* out = (float*)d_out;

    char* ws = (char*)d_ws;
    float4* pos      = (float4*)(ws + 0);
    float2* gh       = (float2*)(ws + 8000000);
    float*  basediff = (float*) (ws + 12000000);
    float*  maskArr  = (float*) (ws + 13600000);
    float*  segdiff  = (float*) (ws + 15200000);
    int*    countp   = (int*)   (ws + 16800000);
    int*    ids      = (int*)   (ws + 16800016);
    double* partials = (double*)(ws + 16816400);

    // zero segdiff + count in one contiguous memset
    hipMemsetAsync(segdiff, 0, 1600004, stream);

    node_kernel<<<NODE_BLOCKS, 256, 0, stream>>>(
        yp, yr, X, be, pos, gh, basediff, maskArr, countp, ids, partials);

    edge_kernel<<<NEDGE / (256 * 4), 256, 0, stream>>>(
        ed, ed + NEDGE, pos, gh, maskArr, segdiff, countp, ids);

    finish_kernel<<<1, 256, 0, stream>>>(
        partials, basediff, segdiff, maskArr, countp, ids, out);
}

// Round 6
// 203.206 us; speedup vs baseline: 4.9832x; 1.0246x over previous
//
#include <hip/hip_runtime.h>
#include <math.h>

#define NVEH 400000
#define NTOT 500000
#define NEDGE 16000000
#define DT 0.2f
#define SAFE_C 1.5f
#define PARK_C 5.0f
#define RADIUS_C 1.5f
#define DEFV_C 2.5f
#define LIST_CAP 4096     // ids stored in ws
#define LIST_USE 128      // LDS-list path iff count <= this
#define REG_USE 16        // registerized compare path iff count <= this

#define NODE_BLOCKS ((NTOT + 255) / 256)         // 1954
#define NODE_WAVES  (NODE_BLOCKS * 4)            // 7816

// ws layout (bytes):
//   pos      @ 0          : NTOT * float4 = 8,000,000   {pred_x,pred_y,ref_x,ref_y}
//   gh       @  8,000,000 : NTOT * float2 = 4,000,000   {g, h}
//   basediff @ 12,000,000 : NVEH * float  = 1,600,000
//   maskArr  @ 13,600,000 : NVEH * float  = 1,600,000   (fallback path only)
//   segdiff  @ 15,200,000 : NVEH * float  = 1,600,000   (zeroed by node for masked ids only)
//   count    @ 16,800,000 : int                          [memset 0 — only 4 bytes]
//   ids      @ 16,800,016 : LIST_CAP * int
//   partials @ 16,816,400 : NODE_WAVES * double = 62,528
//
// g = col7 + R + veh*(|s|+R)  (e0-role),  h = |s| + SAFE  (e1-role)

__global__ __launch_bounds__(256) void node_kernel(
    const float* __restrict__ yp, const float* __restrict__ yr,
    const float* __restrict__ X, const float* __restrict__ be,
    float4* __restrict__ pos, float2* __restrict__ gh,
    float* __restrict__ basediff, float* __restrict__ maskArr,
    float* __restrict__ segdiff,
    int* __restrict__ countp, int* __restrict__ ids,
    double* __restrict__ partials)
{
    __shared__ float sX[256 * 9];                 // 9216 B staging for this block's X rows
    int blk0 = blockIdx.x * 256;
    int nrows = NTOT - blk0; if (nrows > 256) nrows = 256;
    {
        // nrows*9 is divisible by 4 for nrows in {256, 32} (our fixed sizes)
        int nf4 = (nrows * 9) >> 2;
        const float4* src = (const float4*)(X + (size_t)blk0 * 9);
        for (int t = threadIdx.x; t < nf4; t += 256)
            ((float4*)sX)[t] = src[t];
    }
    __syncthreads();

    int i = blk0 + threadIdx.x;
    double local = 0.0;
    if (i < NTOT) {
        const float* row = sX + threadIdx.x * 9;  // 9-stride LDS reads: 2-way bank alias = free
        if (i < NVEH) {
            float x0 = row[0], x1 = row[1], psi = row[2], v = row[3];
            float p4 = row[4], p5 = row[5], x7 = row[7];
            float2 yrv = ((const float2*)yr)[i];
            float2 ypv = ((const float2*)yp)[i];
            float yr0 = yrv.x, yr1 = yrv.y, yp0 = ypv.x, yp1 = ypv.y;

            // vehicle dynamics (psi_t never consumed downstream -> skipped)
            float xt = x0 + v * cosf(psi) * DT;
            float yt = x1 + v * sinf(psi) * DT;
            float vt = 0.99f * v + yr0 * DT;

            // updated speed for collision model
            float speed = vt + (yp0 - yr0) * DT;
            float ct = cosf(yr1), st = sinf(yr1);
            float ppx = xt + ct * speed * DT;
            float ppy = yt + st * speed * DT;

            float as = fabsf(speed);
            pos[i] = make_float4(ppx, ppy, xt, yt);
            gh[i]  = make_float2(x7 + RADIUS_C + as + RADIUS_C, as + SAFE_C);

            float nrm_pred = sqrtf(ppx * ppx + ppy * ppy);
            float nrm_ref  = sqrtf(xt * xt + yt * yt);
            basediff[i] = nrm_pred - nrm_ref;

            // masks
            float dx = xt - p4, dy = yt - p5;
            bool m1 = (sqrtf(dx * dx + dy * dy) - (PARK_C + fabsf(v))) > 0.0f;
            bool m2 = fabsf(vt) >= (DEFV_C - 1e-5f);
            float sg = (vt > 0.0f) ? 1.0f : ((vt < 0.0f) ? -1.0f : 0.0f);
            bool m3 = sg * (yr0 - yp0) <= 1e-5f;
            bool msk = m1 && m2 && m3;
            maskArr[i] = msk ? 1.0f : 0.0f;
            if (msk) {
                segdiff[i] = 0.0f;               // only masked entries are ever read/accumulated
                int idx = atomicAdd(countp, 1);
                if (idx < LIST_CAP) ids[idx] = i;
            }

            // edge-independent loss terms
            float t1 = (yr1 - yp1) * 1.25f;           // / BOUND1 (0.8)
            float l1 = t1 * t1;
            float t2 = yr0 - yp0;                     // / BOUND0 (1.0)
            float l21 = t2 * t2;
            float2 bev = ((const float2*)be)[i];
            float b1s = bev.y * 1.25f;
            float l3 = bev.x * bev.x + b1s * b1s;

            local = (double)l1 + (double)((msk ? 0.0f : 1.0f) * l21) + 0.1 * (double)l3;
        } else {
            float x0 = row[0], x1 = row[1], v = row[3], x7 = row[7];
            pos[i] = make_float4(x0, x1, x0, x1);
            gh[i]  = make_float2(x7 + RADIUS_C, fabsf(v) + SAFE_C);
        }
    }
    // wave-level double reduction -> ONE PLAIN STORE per wave (no atomics)
    for (int off = 32; off > 0; off >>= 1)
        local += __shfl_down(local, off, 64);
    if ((threadIdx.x & 63) == 0)
        partials[blockIdx.x * 4 + (threadIdx.x >> 6)] = local;
}

__device__ __forceinline__ void edge_compute(
    int a, int b, const float4* __restrict__ pos, const float2* __restrict__ gh,
    float* __restrict__ segdiff)
{
    float4 pa = pos[a];
    float4 pb = pos[b];
    float base = gh[a].x + gh[b].y;    // g[a] + h[b]

    float dxp = pa.x - pb.x, dyp = pa.y - pb.y;
    float dp = sqrtf(dxp * dxp + dyp * dyp);
    float lcp = fmaxf(base - dp, 0.0f);

    float dxr = pa.z - pb.z, dyr = pa.w - pb.w;
    float dr = sqrtf(dxr * dxr + dyr * dyr);
    float lcr = fmaxf(base - dr, 0.0f);

    float diff = (lcp * lcp + lcp) - (lcr * lcr + lcr);
    if (diff != 0.0f)
        atomicAdd(segdiff + b, diff);
}

__global__ __launch_bounds__(256) void edge_kernel(
    const int* __restrict__ e0p, const int* __restrict__ e1p,
    const float4* __restrict__ pos, const float2* __restrict__ gh,
    const float* __restrict__ maskArr,
    float* __restrict__ segdiff,
    const int* __restrict__ countp, const int* __restrict__ ids)
{
    __shared__ int s_ids[LIST_USE];
    int cnt = *countp;
    int base = (blockIdx.x * 256 + threadIdx.x) * 4;   // 4 edges per thread

    if (cnt <= LIST_USE) {
        if (threadIdx.x < cnt) s_ids[threadIdx.x] = ids[threadIdx.x];
        __syncthreads();
        int4 bv = *(const int4*)(e1p + base);

        if (cnt <= REG_USE) {
            // branchless registerized membership test (typical: cnt ~ a few)
            int idr[REG_USE];
#pragma unroll
            for (int j = 0; j < REG_USE; ++j)
                idr[j] = (j < cnt) ? s_ids[j] : -1;

            int bs[4] = {bv.x, bv.y, bv.z, bv.w};
#pragma unroll
            for (int k = 0; k < 4; ++k) {
                int b = bs[k];
                bool h = false;
#pragma unroll
                for (int j = 0; j < REG_USE; ++j) h |= (b == idr[j]);
                if (h) {
                    int a = e0p[base + k];
                    edge_compute(a, b, pos, gh, segdiff);
                }
            }
        } else {
            int bs[4] = {bv.x, bv.y, bv.z, bv.w};
#pragma unroll
            for (int k = 0; k < 4; ++k) {
                int b = bs[k];
                bool h = false;
                for (int j = 0; j < cnt; ++j) h |= (b == s_ids[j]);
                if (h) {
                    int a = e0p[base + k];
                    edge_compute(a, b, pos, gh, segdiff);
                }
            }
        }
    } else {
        // robust fallback: per-edge mask gather (statistically never taken)
        for (int k = 0; k < 4; ++k) {
            int b = e1p[base + k];
            if (b < NVEH && maskArr[b] != 0.0f) {
                int a = e0p[base + k];
                edge_compute(a, b, pos, gh, segdiff);
            }
        }
    }
}

__global__ __launch_bounds__(256) void finish_kernel(
    const double* __restrict__ partials,
    const float* __restrict__ basediff, const float* __restrict__ segdiff,
    const float* __restrict__ maskArr,
    const int* __restrict__ countp, const int* __restrict__ ids,
    float* __restrict__ out)
{
    int tid = threadIdx.x;
    // 4 independent accumulators for load ILP over the 7816 partials
    double s0 = 0.0, s1 = 0.0, s2 = 0.0, s3 = 0.0;
    for (int j = tid; j < NODE_WAVES; j += 1024) {
        s0 += partials[j];
        if (j + 256 < NODE_WAVES) s1 += partials[j + 256];
        if (j + 512 < NODE_WAVES) s2 += partials[j + 512];
        if (j + 768 < NODE_WAVES) s3 += partials[j + 768];
    }
    double s = (s0 + s1) + (s2 + s3);

    int cnt = *countp;
    if (cnt <= LIST_CAP) {
        for (int j = tid; j < cnt; j += 256) {
            int i = ids[j];
            float d = basediff[i] + segdiff[i];
            s += (double)((d >= 0.0f) ? (d * d + d) : d);
        }
    } else {
        // slow-but-correct fallback
        for (int i = tid; i < NVEH; i += 256) {
            if (maskArr[i] != 0.0f) {
                float d = basediff[i] + segdiff[i];
                s += (double)((d >= 0.0f) ? (d * d + d) : d);
            }
        }
    }

    // block reduction (4 waves)
    __shared__ double red[4];
    for (int off = 32; off > 0; off >>= 1)
        s += __shfl_down(s, off, 64);
    if ((tid & 63) == 0) red[tid >> 6] = s;
    __syncthreads();
    if (tid == 0) {
        double t = red[0] + red[1] + red[2] + red[3];
        out[0] = (float)(t * (1.0 / (double)NVEH));
    }
}

extern "C" void kernel_launch(void* const* d_in, const int* in_sizes, int n_in,
                              void* d_out, int out_size, void* d_ws, size_t ws_size,
                              hipStream_t stream) {
    const float* yp = (const float*)d_in[0];   // y_pred  (NV,2)
    const float* yr = (const float*)d_in[1];   // y_ref   (NV,2)
    const float* X  = (const float*)d_in[2];   // X_cur   (N,9)
    const int*   ed = (const int*)d_in[3];     // edges   (2,E)
    const float* be = (const float*)d_in[4];   // be_static (NV,2)
    float* out = (float*)d_out;

    char* ws = (char*)d_ws;
    float4* pos      = (float4*)(ws + 0);
    float2* gh       = (float2*)(ws + 8000000);
    float*  basediff = (float*) (ws + 12000000);
    float*  maskArr  = (float*) (ws + 13600000);
    float*  segdiff  = (float*) (ws + 15200000);
    int*    countp   = (int*)   (ws + 16800000);
    int*    ids      = (int*)   (ws + 16800016);
    double* partials = (double*)(ws + 16816400);

    // only the 4-byte counter needs pre-zeroing now
    hipMemsetAsync(countp, 0, 4, stream);

    node_kernel<<<NODE_BLOCKS, 256, 0, stream>>>(
        yp, yr, X, be, pos, gh, basediff, maskArr, segdiff, countp, ids, partials);

    edge_kernel<<<NEDGE / (256 * 4), 256, 0, stream>>>(
        ed, ed + NEDGE, pos, gh, maskArr, segdiff, countp, ids);

    finish_kernel<<<1, 256, 0, stream>>>(
        partials, basediff, segdiff, maskArr, countp, ids, out);
}

// Round 8
// 200.565 us; speedup vs baseline: 5.0488x; 1.0132x over previous
//
#include <hip/hip_runtime.h>
#include <math.h>

#define NVEH 400000
#define NTOT 500000
#define NEDGE 16000000
#define DT 0.2f
#define SAFE_C 1.5f
#define PARK_C 5.0f
#define RADIUS_C 1.5f
#define DEFV_C 2.5f
#define LIST_CAP 4096     // ids stored in ws; LDS membership path iff count <= this
#define REG_USE 16        // registerized compare path iff count <= this

#define MASK_BLOCKS ((NVEH + 255) / 256)         // 1563
#define MASK_WAVES  (MASK_BLOCKS * 4)            // 6252

typedef int vint4 __attribute__((ext_vector_type(4)));   // nontemporal-load-compatible

// ws layout (bytes):
//   maskArr  @ 0         : NVEH * float = 1,600,000   (only for cnt>LIST_CAP fallback)
//   segdiff  @ 1,600,000 : NVEH * float = 1,600,000   (zeroed by mask_kernel for masked ids)
//   count    @ 3,200,000 : int                         [memset 0 — 4 bytes]
//   ids      @ 3,200,016 : LIST_CAP * int = 16,384
//   partials @ 3,216,400 : MASK_WAVES * double = 50,016
//
// pos/gh tables are GONE: edge/finish recompute node state on the fly for the
// ~hundreds of endpoints that ever need it (hit edges + active ids).

// Recompute a node's collision-model state directly from inputs.
// g = col7 + R + veh*(|s|+R)  (e0-role),  h = |s| + SAFE  (e1-role)
__device__ __forceinline__ void node_state(
    int n, const float* __restrict__ X,
    const float* __restrict__ yr, const float* __restrict__ yp,
    float& px, float& py, float& rx, float& ry, float& g, float& h)
{
    const float* row = X + (size_t)n * 9;
    float x0 = row[0], x1 = row[1], x7 = row[7];
    if (n < NVEH) {
        float psi = row[2], v = row[3];
        float yr0 = yr[2 * n], yr1 = yr[2 * n + 1], yp0 = yp[2 * n];
        float xt = x0 + v * cosf(psi) * DT;
        float yt = x1 + v * sinf(psi) * DT;
        float vt = 0.99f * v + yr0 * DT;
        float speed = vt + (yp0 - yr0) * DT;
        float as = fabsf(speed);
        px = xt + cosf(yr1) * speed * DT;
        py = yt + sinf(yr1) * speed * DT;
        rx = xt; ry = yt;
        g = x7 + RADIUS_C + as + RADIUS_C;
        h = as + SAFE_C;
    } else {
        float v = row[3];
        px = rx = x0; py = ry = x1;
        g = x7 + RADIUS_C;
        h = fabsf(v) + SAFE_C;
    }
}

__global__ __launch_bounds__(256) void mask_kernel(
    const float* __restrict__ yp, const float* __restrict__ yr,
    const float* __restrict__ X, const float* __restrict__ be,
    float* __restrict__ maskArr, float* __restrict__ segdiff,
    int* __restrict__ countp, int* __restrict__ ids,
    double* __restrict__ partials)
{
    __shared__ float sX[256 * 9];                 // stage this block's X rows, coalesced
    int blk0 = blockIdx.x * 256;
    int nrows = NVEH - blk0; if (nrows > 256) nrows = 256;   // 256 or 128 -> *9/4 integral
    {
        int nf4 = (nrows * 9) >> 2;
        const float4* src = (const float4*)(X + (size_t)blk0 * 9);
        for (int t = threadIdx.x; t < nf4; t += 256)
            ((float4*)sX)[t] = src[t];
    }
    __syncthreads();

    int i = blk0 + threadIdx.x;
    double local = 0.0;
    if (i < NVEH) {
        const float* row = sX + threadIdx.x * 9;  // stride-9 LDS: 2-way alias = free
        float x0 = row[0], x1 = row[1], psi = row[2], v = row[3];
        float p4 = row[4], p5 = row[5];
        float2 yrv = ((const float2*)yr)[i];
        float2 ypv = ((const float2*)yp)[i];
        float yr0 = yrv.x, yr1 = yrv.y, yp0 = ypv.x, yp1 = ypv.y;

        // vehicle dynamics (psi_t never consumed downstream -> skipped)
        float xt = x0 + v * cosf(psi) * DT;
        float yt = x1 + v * sinf(psi) * DT;
        float vt = 0.99f * v + yr0 * DT;

        // masks
        float dx = xt - p4, dy = yt - p5;
        bool m1 = (sqrtf(dx * dx + dy * dy) - (PARK_C + fabsf(v))) > 0.0f;
        bool m2 = fabsf(vt) >= (DEFV_C - 1e-5f);
        float sg = (vt > 0.0f) ? 1.0f : ((vt < 0.0f) ? -1.0f : 0.0f);
        bool m3 = sg * (yr0 - yp0) <= 1e-5f;
        bool msk = m1 && m2 && m3;
        maskArr[i] = msk ? 1.0f : 0.0f;
        if (msk) {
            segdiff[i] = 0.0f;                   // only masked entries are ever accumulated/read
            int idx = atomicAdd(countp, 1);
            if (idx < LIST_CAP) ids[idx] = i;
        }

        // edge-independent loss terms
        float t1 = (yr1 - yp1) * 1.25f;          // / BOUND1 (0.8)
        float l1 = t1 * t1;
        float t2 = yr0 - yp0;                    // / BOUND0 (1.0)
        float l21 = t2 * t2;
        float2 bev = ((const float2*)be)[i];
        float b1s = bev.y * 1.25f;
        float l3 = bev.x * bev.x + b1s * b1s;

        local = (double)l1 + (double)((msk ? 0.0f : 1.0f) * l21) + 0.1 * (double)l3;
    }
    // wave-level double reduction -> ONE PLAIN STORE per wave (no atomics)
    for (int off = 32; off > 0; off >>= 1)
        local += __shfl_down(local, off, 64);
    if ((threadIdx.x & 63) == 0)
        partials[blockIdx.x * 4 + (threadIdx.x >> 6)] = local;
}

__device__ __forceinline__ void edge_compute(
    int a, int b,
    const float* __restrict__ X, const float* __restrict__ yr,
    const float* __restrict__ yp, float* __restrict__ segdiff)
{
    float pax, pay, rax, ray, ga, ha;
    float pbx, pby, rbx, rby, gb, hb;
    node_state(a, X, yr, yp, pax, pay, rax, ray, ga, ha);
    node_state(b, X, yr, yp, pbx, pby, rbx, rby, gb, hb);

    float base = ga + hb;    // g[a] + h[b]

    float dxp = pax - pbx, dyp = pay - pby;
    float dp = sqrtf(dxp * dxp + dyp * dyp);
    float lcp = fmaxf(base - dp, 0.0f);

    float dxr = rax - rbx, dyr = ray - rby;
    float dr = sqrtf(dxr * dxr + dyr * dyr);
    float lcr = fmaxf(base - dr, 0.0f);

    float diff = (lcp * lcp + lcp) - (lcr * lcr + lcr);
    if (diff != 0.0f)
        atomicAdd(segdiff + b, diff);
}

__global__ __launch_bounds__(256) void edge_kernel(
    const int* __restrict__ e0p, const int* __restrict__ e1p,
    const float* __restrict__ X, const float* __restrict__ yr,
    const float* __restrict__ yp, const float* __restrict__ maskArr,
    float* __restrict__ segdiff,
    const int* __restrict__ countp, const int* __restrict__ ids)
{
    __shared__ int s_ids[LIST_CAP];
    int cnt = *countp;
    int base = (blockIdx.x * 256 + threadIdx.x) * 4;   // 4 edges per thread

    if (cnt <= LIST_CAP) {
        int lim = (cnt < LIST_CAP) ? cnt : LIST_CAP;
        for (int t = threadIdx.x; t < lim; t += 256) s_ids[t] = ids[t];
        __syncthreads();
        vint4 bv = __builtin_nontemporal_load((const vint4*)(e1p + base));

        if (cnt <= REG_USE) {
            // branchless registerized membership test (typical: cnt ~ a few)
            int idr[REG_USE];
#pragma unroll
            for (int j = 0; j < REG_USE; ++j)
                idr[j] = (j < cnt) ? s_ids[j] : -1;

            int bs[4] = {bv.x, bv.y, bv.z, bv.w};
#pragma unroll
            for (int k = 0; k < 4; ++k) {
                int b = bs[k];
                bool h = false;
#pragma unroll
                for (int j = 0; j < REG_USE; ++j) h |= (b == idr[j]);
                if (h) {
                    int a = e0p[base + k];
                    edge_compute(a, b, X, yr, yp, segdiff);
                }
            }
        } else {
            // rare: LDS membership loop over up to 4096 ids
            int bs[4] = {bv.x, bv.y, bv.z, bv.w};
#pragma unroll
            for (int k = 0; k < 4; ++k) {
                int b = bs[k];
                bool h = false;
                for (int j = 0; j < cnt; ++j) h |= (b == s_ids[j]);
                if (h) {
                    int a = e0p[base + k];
                    edge_compute(a, b, X, yr, yp, segdiff);
                }
            }
        }
    } else {
        // robust fallback: per-edge mask gather (statistically never taken)
        for (int k = 0; k < 4; ++k) {
            int b = e1p[base + k];
            if (b < NVEH && maskArr[b] != 0.0f) {
                int a = e0p[base + k];
                edge_compute(a, b, X, yr, yp, segdiff);
            }
        }
    }
}

__global__ __launch_bounds__(256) void finish_kernel(
    const double* __restrict__ partials,
    const float* __restrict__ X, const float* __restrict__ yr,
    const float* __restrict__ yp,
    const float* __restrict__ segdiff, const float* __restrict__ maskArr,
    const int* __restrict__ countp, const int* __restrict__ ids,
    float* __restrict__ out)
{
    int tid = threadIdx.x;
    // 4 independent accumulators for load ILP over the partials
    double s0 = 0.0, s1 = 0.0, s2 = 0.0, s3 = 0.0;
    for (int j = tid; j < MASK_WAVES; j += 1024) {
        s0 += partials[j];
        if (j + 256 < MASK_WAVES) s1 += partials[j + 256];
        if (j + 512 < MASK_WAVES) s2 += partials[j + 512];
        if (j + 768 < MASK_WAVES) s3 += partials[j + 768];
    }
    double s = (s0 + s1) + (s2 + s3);

    int cnt = *countp;
    if (cnt <= LIST_CAP) {
        for (int j = tid; j < cnt; j += 256) {
            int i = ids[j];
            float px, py, rx, ry, g, h;
            node_state(i, X, yr, yp, px, py, rx, ry, g, h);
            float bd = sqrtf(px * px + py * py) - sqrtf(rx * rx + ry * ry);
            float d = bd + segdiff[i];
            s += (double)((d >= 0.0f) ? (d * d + d) : d);
        }
    } else {
        // slow-but-correct fallback
        for (int i = tid; i < NVEH; i += 256) {
            if (maskArr[i] != 0.0f) {
                float px, py, rx, ry, g, h;
                node_state(i, X, yr, yp, px, py, rx, ry, g, h);
                float bd = sqrtf(px * px + py * py) - sqrtf(rx * rx + ry * ry);
                float d = bd + segdiff[i];
                s += (double)((d >= 0.0f) ? (d * d + d) : d);
            }
        }
    }

    // block reduction (4 waves)
    __shared__ double red[4];
    for (int off = 32; off > 0; off >>= 1)
        s += __shfl_down(s, off, 64);
    if ((tid & 63) == 0) red[tid >> 6] = s;
    __syncthreads();
    if (tid == 0) {
        double t = red[0] + red[1] + red[2] + red[3];
        out[0] = (float)(t * (1.0 / (double)NVEH));
    }
}

extern "C" void kernel_launch(void* const* d_in, const int* in_sizes, int n_in,
                              void* d_out, int out_size, void* d_ws, size_t ws_size,
                              hipStream_t stream) {
    const float* yp = (const float*)d_in[0];   // y_pred  (NV,2)
    const float* yr = (const float*)d_in[1];   // y_ref   (NV,2)
    const float* X  = (const float*)d_in[2];   // X_cur   (N,9)
    const int*   ed = (const int*)d_in[3];     // edges   (2,E)
    const float* be = (const float*)d_in[4];   // be_static (NV,2)
    float* out = (float*)d_out;

    char* ws = (char*)d_ws;
    float*  maskArr  = (float*) (ws + 0);
    float*  segdiff  = (float*) (ws + 1600000);
    int*    countp   = (int*)   (ws + 3200000);
    int*    ids      = (int*)   (ws + 3200016);
    double* partials = (double*)(ws + 3216400);

    // only the 4-byte counter needs pre-zeroing
    (void)hipMemsetAsync(countp, 0, 4, stream);

    mask_kernel<<<MASK_BLOCKS, 256, 0, stream>>>(
        yp, yr, X, be, maskArr, segdiff, countp, ids, partials);

    edge_kernel<<<NEDGE / (256 * 4), 256, 0, stream>>>(
        ed, ed + NEDGE, X, yr, yp, maskArr, segdiff, countp, ids);

    finish_kernel<<<1, 256, 0, stream>>>(
        partials, X, yr, yp, segdiff, maskArr, countp, ids, out);
}